// Round 7
// baseline (178.502 us; speedup 1.0000x reference)
//
#include <hip/hip_runtime.h>
#include <stdint.h>

// YoloNAS postprocess, fp32 in/out — R15 (= R13 re-anchor + wave-combined bins16 store).
// memset | k_conf (2048 blk): conf/argmax -> bins16 + SWIZZLED 32k hist (depth-4 MLP ring)
//        | k_gather (64 blk x 1024 thr): inlined register-held cutoff + candidate emit
//        | k_final (1 blk): counting-rank sort (bitonic fallback) -> popcount-rank
//          class grouping -> grouped-order suppression -> 80-lane greedy -> output
// R15 vs R14: cooperative kernel REMOVED — hipLaunchCooperativeKernel is not
// capturable by the harness's graph capture (container failed twice). Grid-wide
// sync is unavailable in this harness; fusion stops at kernel boundaries.
// R15 vs R13 (proven 177.2us): only change is k_conf's bins16 store — the 4
// per-wave u16 stores are shfl-combined into one u64 store (bit-identical image).

#define N_ANCH   262144
#define N_CLS    80
#define K_TOP    1024
#define CAP      4096

typedef unsigned long long ull;

// hist layout bijection: bit-rotate 15-bit bin, b = [b14..b11 | b10..b0]
// -> slot = [b10..b0 | b14..b11]. Value-adjacent bins land 16 u32 (64B) apart.
#define HSLOT(b) ((((b) & 2047u) << 4) | ((b) >> 11))
// skewed LDS index for the u64 sort scratch (bitonic 4096 path only)
#define SKEW(e) ((uint32_t)(e) + ((uint32_t)(e) >> 4))

// ---- workspace layout (bytes); total 688192 < proven ws_size >= 733248 ----
#define OFF_HIST  0           // u32[32768] (swizzled layout)
#define OFF_CTRL  131072      // u32[16]: [0]=cand counter, [1]=nsel
#define MEMSET_BYTES 131136
#define OFF_BINS  131136      // u16[262144]: valid?0x8000|bin:0
#define OFF_LIST  655424      // u64[4096] candidate keys
#define WS_REQUIRED 688192

__global__ __launch_bounds__(256) void k_sentinel(float* __restrict__ out, float v) {
    int i = blockIdx.x * 256 + threadIdx.x;
    if (i < K_TOP * 6) out[i] = v;
}

static __device__ __forceinline__ uint32_t conf_key24(float best) {
    uint32_t u = __float_as_uint(best);
    if (u > 0x3F800000u) u = 0x3F800000u;    // defensive; conf in [0.5, 1]
    if (u < 0x3F000000u) u = 0x3F000000u;
    return u - 0x3F000000u;                  // 0..0x800000, monotone in conf
}

static __device__ __forceinline__ void cmpsw(ull& x, ull& y, bool up) {
    ull mn = x < y ? x : y, mx = x < y ? y : x;
    x = up ? mn : mx; y = up ? mx : mn;
}

// ---------- kernel 1: conf/argmax, 16 lanes/anchor, 128 anchors/block ----------
__global__ __launch_bounds__(256) void k_conf(const float* __restrict__ scores,
                                              uint16_t* __restrict__ bins16,
                                              uint32_t* __restrict__ hist) {
    const int t = threadIdx.x;
    const int r = t >> 4, s = t & 15;
    const int a0 = blockIdx.x * 128 + r;
    const float* base = scores + (size_t)a0 * N_CLS;
    // depth-4 software pipeline: 8 (v0) + 2 (v1, s<4) loads in flight per lane group
    float4 v0[4], v1[4];
    #pragma unroll
    for (int p = 0; p < 4; p++) {
        const float* nb = base + (size_t)p * 16 * N_CLS;
        v0[p] = ((const float4*)nb)[s];
        if (s < 4) v1[p] = ((const float4*)nb)[16 + s];
    }
    #pragma unroll
    for (int i = 0; i < 8; i++) {
        float4 c0 = v0[i & 3], c1 = v1[i & 3];
        if (i + 4 < 8) {                              // refill ring 4 tiles ahead
            const float* nb = base + (size_t)(i + 4) * 16 * N_CLS;
            v0[i & 3] = ((const float4*)nb)[s];
            if (s < 4) v1[i & 3] = ((const float4*)nb)[16 + s];
        }
        float best = c0.x; int lab = 4 * s;           // first-max (strict >)
        if (c0.y > best) { best = c0.y; lab = 4 * s + 1; }
        if (c0.z > best) { best = c0.z; lab = 4 * s + 2; }
        if (c0.w > best) { best = c0.w; lab = 4 * s + 3; }
        if (s < 4) {
            const int c = 64 + 4 * s;
            if (c1.x > best) { best = c1.x; lab = c; }
            if (c1.y > best) { best = c1.y; lab = c + 1; }
            if (c1.z > best) { best = c1.z; lab = c + 2; }
            if (c1.w > best) { best = c1.w; lab = c + 3; }
        }
        ull key = ((ull)(uint32_t)__float_as_uint(best) << 7) | (ull)(uint32_t)(127 - lab);
        ull o;
        o = __shfl_xor(key, 1); if (o > key) key = o;
        o = __shfl_xor(key, 2); if (o > key) key = o;
        o = __shfl_xor(key, 4); if (o > key) key = o;
        o = __shfl_xor(key, 8); if (o > key) key = o;
        uint32_t pk = 0;
        if (s == 0) {
            float bv = __uint_as_float((uint32_t)(key >> 7));
            if (bv >= 0.5f) {
                uint32_t bin = conf_key24(bv) >> 8;
                if (bin > 32767u) bin = 32767u;
                atomicAdd(&hist[HSLOT(bin)], 1u);     // swizzled slot, linear bin number
                pk = 0x8000u | bin;
            }
        }
        // wave-combine the 4 writers' u16 into one u64 store (bit-identical image)
        uint32_t p0 = __shfl(pk, 0),  p1 = __shfl(pk, 16);
        uint32_t p2 = __shfl(pk, 32), p3 = __shfl(pk, 48);
        if ((t & 63) == 0) {
            ull v = (ull)(uint16_t)p0 | ((ull)(uint16_t)p1 << 16)
                  | ((ull)(uint16_t)p2 << 32) | ((ull)(uint16_t)p3 << 48);
            const int abase = a0 + i * 16;            // lane0: a0 = blk*128 + 4w, %4==0
            ((ull*)bins16)[abase >> 2] = v;
        }
    }
}

// ---------- kernel 2: cutoff (per-block, reg-held) + candidate emit ----------
// 64 blocks x 1024 threads, 4 anchors/thread. Cutoff logic run redundantly per
// block (~1us of L2-resident hist reads) -> no separate k_cut launch.
__global__ __launch_bounds__(1024) void k_gather(const float* __restrict__ scores,
                                                 const uint16_t* __restrict__ bins16,
                                                 const uint32_t* __restrict__ hist,
                                                 uint32_t* __restrict__ ctrl,
                                                 ull* __restrict__ list) {
    __shared__ uint32_t wtot[16], wsuf[16], shCT, lcnt, lbase;
    const int t = threadIdx.x, b = blockIdx.x;
    const int lane = t & 63, w = t >> 6;
    if (t == 0) { shCT = 0; lcnt = 0; lbase = 0; }
    // ---- cutoff: thread t owns bins [32t, 32t+32) in registers ----
    // bins b15 = 32t + i: slot = ((t&63)<<9) | (i<<4) | (t>>6)
    const uint32_t sbase = (((uint32_t)t & 63u) << 9) | ((uint32_t)t >> 6);
    uint32_t c[32];
    #pragma unroll
    for (int i = 0; i < 32; i++) c[i] = hist[sbase | ((uint32_t)i << 4)];
    uint32_t part = 0;
    #pragma unroll
    for (int i = 0; i < 32; i++) part += c[i];
    uint32_t x = part;                                // wave inclusive suffix scan
    #pragma unroll
    for (int d = 1; d < 64; d <<= 1) {
        uint32_t o = __shfl_down(x, d);
        if (lane + d < 64) x += o;
    }
    if (lane == 0) wtot[w] = x;
    __syncthreads();
    if (t < 16) {
        uint32_t s = 0;
        for (int ww = t + 1; ww < 16; ww++) s += wtot[ww];
        wsuf[t] = s;                                  // waves strictly above
        if (t == 0 && b == 0) {
            uint32_t total = s + wtot[0];
            ctrl[1] = (total < K_TOP) ? total : K_TOP;   // nsel (written once)
        }
    }
    __syncthreads();
    {
        uint32_t run = (x + wsuf[w]) - part;          // count strictly above my segment
        if (run < K_TOP && run + part >= K_TOP) {     // unique crossing thread
            uint32_t fnd = 0, cbv = 0;
            #pragma unroll
            for (int i = 31; i >= 0; i--) {           // descending bins, register scan
                if (!fnd && run + c[i] >= K_TOP) { cbv = (uint32_t)(t * 32 + i); fnd = 1; }
                if (!fnd) run += c[i];
            }
            shCT = cbv;
        }
        // total < K_TOP: no writer; shCT stays 0 -> include everything
    }
    __syncthreads();
    const uint32_t cT = shCT;

    // ---- scan my 4-anchor slice, re-derive exact keys for hits ----
    const int a4 = b * 1024 + t;
    ushort4 pk4 = ((const ushort4*)bins16)[a4];
    uint16_t pk[4] = {pk4.x, pk4.y, pk4.z, pk4.w};
    ull      hk[4];                                   // keys  (compile-time indexed)
    uint32_t hs[4];                                   // local slots
    bool     hv[4];                                   // valid
    #pragma unroll
    for (int e = 0; e < 4; e++) {
        hv[e] = false; hk[e] = 0; hs[e] = 0;
        uint32_t u = pk[e];
        if ((u & 0x8000u) && (u & 0x7FFFu) >= cT) {
            const uint32_t a = (uint32_t)a4 * 4u + (uint32_t)e;
            const float4* row = (const float4*)(scores + (size_t)a * N_CLS);
            float best = -1.f; int lab = 0;
            for (int f = 0; f < 20; f++) {
                float4 w2 = row[f];
                if (w2.x > best) { best = w2.x; lab = 4 * f; }
                if (w2.y > best) { best = w2.y; lab = 4 * f + 1; }
                if (w2.z > best) { best = w2.z; lab = 4 * f + 2; }
                if (w2.w > best) { best = w2.w; lab = 4 * f + 3; }
            }
            if (best >= 0.5f) {
                uint32_t k24 = conf_key24(best);
                hk[e] = ((ull)(0x1000000u - k24) << 25) | ((ull)a << 7)
                      | (ull)(uint32_t)lab;           // ascending = conf desc, idx asc
                hs[e] = atomicAdd(&lcnt, 1u);         // LDS: ~20 hits/block
                hv[e] = true;
            }
        }
    }
    __syncthreads();
    if (t == 0 && lcnt) lbase = atomicAdd(&ctrl[0], lcnt);  // ONE global atomic/block
    __syncthreads();
    const uint32_t base2 = lbase;
    #pragma unroll
    for (int e = 0; e < 4; e++) {
        if (hv[e]) {
            uint32_t slot = base2 + hs[e];
            if (slot < CAP) list[slot] = hk[e];       // list order irrelevant: k_final sorts
        }
    }
}

// ---------- kernel 3: sort + group + grouped-order NMS + output (1 block) ----------
// LDS (sort phase): sk u64[4352]@0 (34816B) | hist2 u32[2048]@34816 | gfail@43008 |
//   wtot2[16]@43012 | wbase[16]@43076
// LDS (post-sort, sequential reuse): ob f4[1024]@0 | obg f4[1024]@16384 |
//   ar f[1024]@32768 | arg f[1024]@36864 | red16 f[16]@40960 | g u32[1024]@41024 |
//   sup u64[1024]@45120 | keepA u8[1024]@53312 | cnt u32[80]@54336 |
//   stt u32[80]@54656 | cmask u64[80][16]@54976 (ends 65216)
__global__ __launch_bounds__(1024) void k_final(const float4* __restrict__ bboxes,
                                                const uint32_t* __restrict__ ctrl,
                                                const ull* __restrict__ list,
                                                float* __restrict__ out) {
    __shared__ __align__(16) char smem[65280];
    ull*      sk    = (ull*)smem;
    float4*   ob    = (float4*)smem;
    float4*   obg   = (float4*)(smem + 16384);
    float*    ar    = (float*)(smem + 32768);
    float*    arg   = (float*)(smem + 36864);
    float*    red16 = (float*)(smem + 40960);
    uint32_t* g     = (uint32_t*)(smem + 41024);
    ull*      sup   = (ull*)(smem + 45120);
    uint8_t*  keepA = (uint8_t*)(smem + 53312);
    uint32_t* cnt   = (uint32_t*)(smem + 54336);
    uint32_t* stt   = (uint32_t*)(smem + 54656);
    ull*      cmask = (ull*)(smem + 54976);           // [80][16] bit t = rank t present
    uint32_t* hist2 = (uint32_t*)(smem + 34816);      // sort phase only
    uint32_t* gfail = (uint32_t*)(smem + 43008);
    uint32_t* wtot2 = (uint32_t*)(smem + 43012);
    uint32_t* wbase = (uint32_t*)(smem + 43076);
    const int t = threadIdx.x;
    const uint32_t nsel = ctrl[1];
    uint32_t ncand = ctrl[0]; if (ncand > CAP) ncand = CAP;

    // ================= counting-rank sort (fast path) =================
    // Candidate keys: k24c = (key>>25)-0x800000 expected < ~1100 (cutoff ~4 fine
    // bins below top). Rank = #smaller (k24c, anchor).
    ((uint2*)hist2)[t] = make_uint2(0u, 0u);          // zero 2048 slots
    if (t == 0) *gfail = 0;
    __syncthreads();
    ull      keys[4]; uint32_t kcs[4], olds[4]; bool val[4];
    #pragma unroll
    for (int e = 0; e < 4; e++) {
        int i = t + 1024 * e;
        val[e] = (i < (int)ncand); keys[e] = 0; kcs[e] = 0; olds[e] = 0;
        if (val[e]) {
            ull kk = list[i];
            keys[e] = kk;
            uint32_t kc = (uint32_t)(kk >> 25) - 0x800000u;
            if (kc >= 2048u) { *gfail = 1; val[e] = false; }
            else {
                kcs[e] = kc;
                uint32_t od = atomicAdd(&hist2[kc], 1u);
                olds[e] = od;
                if (od >= 16u) *gfail = 1;            // slot too deep: fallback
            }
        }
    }
    __syncthreads();
    const bool ctOK = (*gfail == 0);                  // uniform across block

    if (ctOK) {
        // ---- exclusive prefix over 2048 slots (2/thread, wave scan) ----
        uint32_t v0h = hist2[2 * t], v1h = hist2[2 * t + 1];
        uint32_t sseg = v0h + v1h;
        uint32_t incl = sseg;
        const int lane = t & 63, w = t >> 6;
        #pragma unroll
        for (int d = 1; d < 64; d <<= 1) {
            uint32_t o = __shfl_up(incl, d);
            if (lane >= d) incl += o;
        }
        if (lane == 63) wtot2[w] = incl;
        __syncthreads();
        if (t < 16) {
            uint32_t sb = 0;
            for (int i = 0; i < 16; i++) { uint32_t v = wtot2[i]; if (i < t) sb += v; }
            wbase[t] = sb;
        }
        __syncthreads();
        uint32_t ex = wbase[w] + incl - sseg;         // exclusive before slot 2t
        hist2[2 * t]     = ex;
        hist2[2 * t + 1] = ex + v0h;
        __syncthreads();
        // ---- scatter to rank (arrival order within slot) ----
        #pragma unroll
        for (int e = 0; e < 4; e++)
            if (val[e]) sk[hist2[kcs[e]] + olds[e]] = keys[e];
        __syncthreads();
        // ---- per-slot tie fix-up: insertion sort slots with >=2 (rare) ----
        #pragma unroll
        for (int e = 0; e < 4; e++) {
            if (val[e] && olds[e] == 0) {
                uint32_t base = hist2[kcs[e]];
                uint32_t nxt  = (kcs[e] < 2047u) ? hist2[kcs[e] + 1] : ncand;
                if (nxt - base >= 2u) {
                    for (uint32_t a2 = base + 1; a2 < nxt; a2++) {
                        ull kv = sk[a2];
                        uint32_t b2 = a2;
                        while (b2 > base && sk[b2 - 1] > kv) { sk[b2] = sk[b2 - 1]; b2--; }
                        sk[b2] = kv;
                    }
                }
            }
        }
    } else {
        // ================= bitonic fallback (R11 code, unchanged) =================
        uint32_t nsort = 1024;
        while (nsort < ncand) nsort <<= 1;            // 1024 / 2048 / 4096 (uniform)
        if (nsort <= 2048) {
            const int TS2 = (int)(nsort >> 1);
            ull E0 = ~0ull, E1 = ~0ull;
            if (t < TS2) {
                int e = 2 * t;
                E0 = (e < (int)ncand)     ? list[e]     : ~0ull;
                E1 = (e + 1 < (int)ncand) ? list[e + 1] : ~0ull;
            }
            for (uint32_t k = 2; k <= nsort; k <<= 1) {
                for (uint32_t j = k >> 1; j > 0; j >>= 1) {
                    if (j >= 128) {
                        __syncthreads();
                        if (t < TS2) {
                            ulonglong2 wv; wv.x = E0; wv.y = E1;
                            *(ulonglong2*)&sk[2 * t] = wv;
                        }
                        __syncthreads();
                        if (t < TS2) {
                            uint32_t e0 = 2 * t;
                            ulonglong2 rv = *(const ulonglong2*)&sk[e0 ^ j];
                            bool km = (((e0 & k) == 0) != ((e0 & j) == 0));
                            E0 = ((E0 > rv.x) == km) ? E0 : rv.x;
                            E1 = ((E1 > rv.y) == km) ? E1 : rv.y;
                        }
                    } else if (t < TS2) {
                        if (j >= 2) {
                            int d = (int)(j >> 1);
                            bool km = ((((2 * t) & k) == 0) != (((2 * t) & j) == 0));
                            ull o0 = __shfl_xor(E0, d);
                            ull o1 = __shfl_xor(E1, d);
                            E0 = ((E0 > o0) == km) ? E0 : o0;
                            E1 = ((E1 > o1) == km) ? E1 : o1;
                        } else {
                            bool up = (((2 * t) & k) == 0);
                            cmpsw(E0, E1, up);
                        }
                    }
                }
            }
            __syncthreads();
            if (t < TS2) {
                ulonglong2 wv; wv.x = E0; wv.y = E1;
                *(ulonglong2*)&sk[2 * t] = wv;
            }
        } else {
            const int TS = (int)(nsort >> 2);
            ull E[4];
            if (t < TS) {
                #pragma unroll
                for (int rr = 0; rr < 4; rr++) {
                    int e = 4 * t + rr;
                    E[rr] = (e < (int)ncand) ? list[e] : ~0ull;
                }
            }
            for (uint32_t k = 2; k <= nsort; k <<= 1) {
                for (uint32_t j = k >> 1; j > 0; j >>= 1) {
                    if (j >= 256) {
                        __syncthreads();
                        if (t < TS) {
                            #pragma unroll
                            for (int rr = 0; rr < 4; rr++) sk[SKEW(4 * t + rr)] = E[rr];
                        }
                        __syncthreads();
                        if (t < TS) {
                            #pragma unroll
                            for (int rr = 0; rr < 4; rr++) {
                                uint32_t e = 4 * t + rr;
                                ull o = sk[SKEW(e ^ j)];
                                bool keepMax = (((e & k) == 0) != ((e & j) == 0));
                                bool gt = E[rr] > o;
                                E[rr] = (gt == keepMax) ? E[rr] : o;
                            }
                        }
                    } else if (t < TS) {
                        if (j >= 4) {
                            int d = (int)(j >> 2);
                            #pragma unroll
                            for (int rr = 0; rr < 4; rr++) {
                                uint32_t e = 4 * t + rr;
                                ull o = __shfl_xor(E[rr], d);
                                bool keepMax = (((e & k) == 0) != ((e & j) == 0));
                                bool gt = E[rr] > o;
                                E[rr] = (gt == keepMax) ? E[rr] : o;
                            }
                        } else if (j == 2) {
                            bool up = (((4 * t) & k) == 0);
                            cmpsw(E[0], E[2], up); cmpsw(E[1], E[3], up);
                        } else {
                            bool upA = (((4 * t) & k) == 0);
                            bool upB = (((4 * t + 2) & k) == 0);
                            cmpsw(E[0], E[1], upA);
                            cmpsw(E[2], E[3], upB);
                        }
                    }
                }
            }
            __syncthreads();
            if (t < TS) {
                #pragma unroll
                for (int rr = 0; rr < 4; rr++) sk[SKEW(4 * t + rr)] = E[rr];
            }
        }
    }
    __syncthreads();
    ull skey;
    if (ctOK) skey = sk[t];
    else {
        uint32_t nsort = 1024;
        while (nsort < ncand) nsort <<= 1;
        skey = (nsort <= 2048) ? sk[t] : sk[SKEW(t)];
    }
    __syncthreads();                                  // sk region free for reuse

    // ---- extract + gather + prep (exact reference fp32 order; max is associative) ----
    float4 bx = make_float4(0.f, 0.f, 0.f, 0.f);
    float cf = 0.f, lb = 0.f;
    uint32_t lab = 0;
    if ((uint32_t)t < nsel) {
        uint32_t idx = (uint32_t)(skey >> 7) & 0x3FFFFu;
        lab = (uint32_t)skey & 127u;
        cf = __uint_as_float(0x3F000000u + (0x1000000u - (uint32_t)(skey >> 25)));
        lb = (float)lab;
        bx = bboxes[idx];
    }
    float m = fmaxf(fmaxf(bx.x, bx.y), fmaxf(bx.z, bx.w));
    for (int d = 32; d > 0; d >>= 1) m = fmaxf(m, __shfl_xor(m, d));
    if ((t & 63) == 0) red16[t >> 6] = m;
    __syncthreads();
    float M = red16[0];
    #pragma unroll
    for (int w = 1; w < 16; w++) M = fmaxf(M, red16[w]);
    M = __fadd_rn(M, 1.0f);
    float o = __fmul_rn(lb, M);
    float4 q;
    q.x = __fadd_rn(bx.x, o); q.y = __fadd_rn(bx.y, o);
    q.z = __fadd_rn(bx.z, o); q.w = __fadd_rn(bx.w, o);
    ob[t] = q;
    ar[t] = __fmul_rn(__fsub_rn(q.z, q.x), __fsub_rn(q.w, q.y));
    g[t] = 0xFFFFFFFFu;                               // scatter target, init invalid
    keepA[t] = 0;
    if (t < 640) {                                    // zero cmask[80][16] (1280 u64)
        ulonglong2 z; z.x = 0; z.y = 0;
        *(ulonglong2*)&cmask[2 * t] = z;
    }
    __syncthreads();

    // ---- popcount-rank class grouping ----
    // g := stable partition by class of the rank-sorted sequence; bit-identical
    // to sorting (lab<<10|t) ascending.
    if ((uint32_t)t < nsel)
        atomicOr(&cmask[lab * 16 + (t >> 6)], 1ull << (t & 63));
    __syncthreads();
    if (t < N_CLS) {                                  // per-class counts
        uint32_t s = 0;
        #pragma unroll
        for (int w = 0; w < 16; w++) s += (uint32_t)__popcll(cmask[t * 16 + w]);
        cnt[t] = s;
    }
    __syncthreads();
    if (t < N_CLS) {                                  // exclusive prefix (starts)
        uint32_t s = 0;
        for (int i = 0; i < N_CLS - 1; i++) {
            uint32_t v = cnt[i];                      // broadcast read
            if (i < t) s += v;
        }
        stt[t] = s;
    }
    __syncthreads();
    if ((uint32_t)t < nsel) {                         // within-class rank + scatter
        const ull* cm = &cmask[lab * 16];
        uint32_t w = (uint32_t)t >> 6;
        uint32_t r = (uint32_t)__popcll(cm[w] & ((1ull << (t & 63)) - 1ull));
        for (uint32_t ww = 0; ww < w; ww++) r += (uint32_t)__popcll(cm[ww]);
        g[stt[lab] + r] = (lab << 10) | (uint32_t)t;
    }
    __syncthreads();

    // ---- materialize boxes/areas in GROUPED order (one indirection, once) ----
    uint32_t gp = g[t];
    if (gp != 0xFFFFFFFFu) {
        uint32_t ri = gp & 1023u;
        obg[t] = ob[ri];
        arg[t] = ar[ri];
    }
    __syncthreads();

    // ---- suppression bitmask: delta loop, address-predictable LDS reads ----
    {
        ull sp = 0;
        if (gp != 0xFFFFFFFFu) {
            uint32_t labi = gp >> 10;
            uint32_t nsucc = cnt[labi] - (uint32_t)(t - stt[labi]) - 1u;
            uint32_t trips = nsucc > 64u ? 64u : nsucc;
            float4 oi = obg[t]; float ai = arg[t];
            #pragma unroll 4
            for (uint32_t d = 1; d <= trips; d++) {
                float4 oj = obg[t + d];
                float aj = arg[t + d];
                float lx = fmaxf(oi.x, oj.x), ly = fmaxf(oi.y, oj.y);
                float rx = fminf(oi.z, oj.z), ry = fminf(oi.w, oj.w);
                float wx = fmaxf(__fsub_rn(rx, lx), 0.f);
                float wy = fmaxf(__fsub_rn(ry, ly), 0.f);
                float inter = __fmul_rn(wx, wy);
                float uni = __fsub_rn(__fadd_rn(ai, aj), inter);
                float iou = __fdiv_rn(inter, fmaxf(uni, 1e-9f));
                if (iou > 0.6f) sp |= 1ull << (d - 1);
            }
        }
        sup[t] = sp;
    }
    __syncthreads();

    // ---- 80-lane register greedy (rank order within class = score order) ----
    if (t < N_CLS) {
        uint32_t n = cnt[t];
        if (n > 0) {
            uint32_t s0 = stt[t];
            if (n <= 64) {                            // bitmask path (ovr was redundant)
                ull kill = 0;
                for (uint32_t i = 0; i < n; i++) {
                    if (!((kill >> i) & 1ull)) {
                        if (i + 1 < 64) kill |= sup[s0 + i] << (i + 1);
                        keepA[g[s0 + i] & 1023u] = 1;
                    }
                }
            } else {                                  // oversized class: serial fallback
                for (uint32_t i = 0; i < n; i++) {
                    uint32_t ri = g[s0 + i] & 1023u;
                    float4 oi = obg[s0 + i]; float ai = arg[s0 + i];
                    bool kp = true;
                    for (uint32_t m2 = 0; m2 < i && kp; m2++) {
                        if (!keepA[g[s0 + m2] & 1023u]) continue;
                        float4 om = obg[s0 + m2];
                        float lx = fmaxf(om.x, oi.x), ly = fmaxf(om.y, oi.y);
                        float rx = fminf(om.z, oi.z), ry = fminf(om.w, oi.w);
                        float wx = fmaxf(__fsub_rn(rx, lx), 0.f);
                        float wy = fmaxf(__fsub_rn(ry, ly), 0.f);
                        float inter = __fmul_rn(wx, wy);
                        float uni = __fsub_rn(__fadd_rn(arg[s0 + m2], ai), inter);
                        float iou = __fdiv_rn(inter, fmaxf(uni, 1e-9f));
                        if (iou > 0.6f) kp = false;
                    }
                    keepA[ri] = kp ? 1 : 0;
                }
            }
        }
    }
    __syncthreads();

    // ---- masked fp32 output ----
    const bool keep = keepA[t] != 0;
    float v0 = keep ? bx.x : 0.f, v1 = keep ? bx.y : 0.f;
    float v2 = keep ? bx.z : 0.f, v3 = keep ? bx.w : 0.f;
    float v4 = keep ? cf : 0.f, v5 = keep ? lb : 0.f;
    float2* o2 = (float2*)out;
    o2[t * 3 + 0] = make_float2(v0, v1);
    o2[t * 3 + 1] = make_float2(v2, v3);
    o2[t * 3 + 2] = make_float2(v4, v5);
}

extern "C" void kernel_launch(void* const* d_in, const int* in_sizes, int n_in,
                              void* d_out, int out_size, void* d_ws, size_t ws_size,
                              hipStream_t stream) {
    const float* bboxes = (const float*)d_in[0];
    const float* scores = (const float*)d_in[1];
    if (n_in >= 2 && in_sizes[0] > in_sizes[1]) {   // defensive: scores is the 20x larger input
        bboxes = (const float*)d_in[1];
        scores = (const float*)d_in[0];
    }

    if (ws_size < (size_t)WS_REQUIRED) {
        k_sentinel<<<(K_TOP * 6 + 255) / 256, 256, 0, stream>>>(
            (float*)d_out, (float)(ws_size >> 10));
        return;
    }

    char* ws = (char*)d_ws;
    uint32_t* hist   = (uint32_t*)(ws + OFF_HIST);
    uint32_t* ctrl   = (uint32_t*)(ws + OFF_CTRL);
    uint16_t* bins16 = (uint16_t*)(ws + OFF_BINS);
    ull*      list   = (ull*)(ws + OFF_LIST);

    hipMemsetAsync(ws, 0, MEMSET_BYTES, stream);    // hist + ctrl
    k_conf  <<<N_ANCH / 128, 256, 0, stream>>>(scores, bins16, hist);
    k_gather<<<64,          1024, 0, stream>>>(scores, bins16, hist, ctrl, list);
    k_final <<<1,           1024, 0, stream>>>((const float4*)bboxes, ctrl, list,
                                               (float*)d_out);
}